// Round 6
// baseline (223.131 us; speedup 1.0000x reference)
//
#include <hip/hip_runtime.h>
#include <math.h>

constexpr int L = 32768;
constexpr int H = 256;
constexpr int P = 256;
constexpr int T = 64;        // scan chunk length == GEMM row tile
constexpr int NC = L / T;    // 512 chunks
constexpr int N1 = 2 * P;    // 512: X concat width, INTERLEAVED col = 2p+{0:re,1:im}
constexpr int LDEP = 130;    // epilogue LDS row stride (floats)

typedef __attribute__((ext_vector_type(8))) short short8;
typedef __attribute__((ext_vector_type(4))) float f32x4;
typedef union { short8 s; uint4 u; } s8u4;

// ---------------- bf16 helpers (RNE) ----------------
__device__ __forceinline__ unsigned f2bf(float f) {
  unsigned u = __float_as_uint(f);
  return (u + 0x7FFFu + ((u >> 16) & 1u)) >> 16;
}
__device__ __forceinline__ float bf_lo(unsigned u) { return __uint_as_float(u << 16); }
__device__ __forceinline__ float bf_hi(unsigned u) { return __uint_as_float(u & 0xFFFF0000u); }

__device__ __forceinline__ void lambda_bar_of(const float* __restrict__ lam,
                                              const float* __restrict__ lstep,
                                              int p, float& lbr, float& lbi) {
  float lr = lam[2 * p], li = lam[2 * p + 1];
  float st = expf(lstep[p]);
  float ea = expf(lr * st);
  lbr = ea * cosf(li * st);
  lbi = ea * sinf(li * st);
}

// ---------------------------------------------------------------------------
// k_prep2: fused sig->bf16 conversion (blocks 0..4095) + parameter prep
// (blocks 4096..5183): Bcat (512x256 bf16, rows 2p/2p+1 = Re/Im B_bar),
// Ccat (256x512 bf16, cols 2p/2p+1 = Re/-Im C), pow (TxP fp32 planar).
// ---------------------------------------------------------------------------
__global__ __launch_bounds__(256) void k_prep2(const float* __restrict__ sig,
                                               const float* __restrict__ lam,
                                               const float* __restrict__ lstep,
                                               const float* __restrict__ Bri,
                                               const float* __restrict__ Cri,
                                               unsigned short* __restrict__ sigbf,
                                               unsigned short* __restrict__ Bcat,
                                               unsigned short* __restrict__ Ccat,
                                               float* __restrict__ powr,
                                               float* __restrict__ powi) {
  const int bx = blockIdx.x;
  if (bx < 4096) {
    int i = bx * 256 + threadIdx.x;  // < L*H/8
    const float4* ip = (const float4*)sig;
    float4 a = ip[2 * i], b = ip[2 * i + 1];
    uint4 o;
    o.x = f2bf(a.x) | (f2bf(a.y) << 16);
    o.y = f2bf(a.z) | (f2bf(a.w) << 16);
    o.z = f2bf(b.x) | (f2bf(b.y) << 16);
    o.w = f2bf(b.z) | (f2bf(b.w) << 16);
    ((uint4*)sigbf)[i] = o;
    return;
  }
  int idx = (bx - 4096) * 256 + threadIdx.x;  // < 278528
  if (idx < N1 * H) {
    int n = idx >> 8, k = idx & 255;
    int p = n >> 1, comp = n & 1;
    float lr = lam[2 * p], li = lam[2 * p + 1];
    float st = expf(lstep[p]);
    float ea = expf(lr * st);
    float lbr = ea * cosf(li * st), lbi = ea * sinf(li * st);
    float inv = 1.0f / (lr * lr + li * li);
    float nr = lbr - 1.0f;
    float fr = (nr * lr + lbi * li) * inv;
    float fi = (lbi * lr - nr * li) * inv;
    float br = Bri[2 * (p * H + k)], bi = Bri[2 * (p * H + k) + 1];
    float v = (comp == 0) ? (fr * br - fi * bi) : (fr * bi + fi * br);
    Bcat[idx] = (unsigned short)f2bf(v);
  } else if (idx < 2 * N1 * H) {
    int j = idx - N1 * H;
    int h = j >> 9, k2 = j & 511;
    int p = k2 >> 1;
    float v = ((k2 & 1) == 0) ? Cri[2 * (h * P + p)] : -Cri[2 * (h * P + p) + 1];
    Ccat[j] = (unsigned short)f2bf(v);
  } else {
    int r = idx - 2 * N1 * H;  // < T*P
    int t = r >> 8, p = r & 255;
    float lr = lam[2 * p], li = lam[2 * p + 1];
    float st = expf(lstep[p]);
    float e = (float)(t + 1);
    float er = expf(e * lr * st);
    powr[r] = er * cosf(e * li * st);
    powi[r] = er * sinf(e * li * st);
  }
}

// ---------------------------------------------------------------------------
// GEMM1: barrier-free K-loop. Tile 64x128 (1 chunk), 4 waves of 32x64.
// A (sigbf) and B (Bcat, L2-resident) loaded straight into MFMA fragment
// registers — no LDS, no __syncthreads in the K-loop. LDS only for the
// scan epilogue (33 KB). grid (N1/128, NC) = (4, 512).
// ---------------------------------------------------------------------------
__global__ __launch_bounds__(256) void k_gemm1(const unsigned short* __restrict__ sigbf,
                                               const unsigned short* __restrict__ Bcat,
                                               const float* __restrict__ lam,
                                               const float* __restrict__ lstep,
                                               unsigned short* __restrict__ Xl,
                                               float* __restrict__ Sr,
                                               float* __restrict__ Si) {
  constexpr int K = 256;
  __shared__ __align__(16) float sEpi[T * LDEP];   // 33.3 KB
  const int tid = threadIdx.x;
  const int lane = tid & 63;
  const int wave = tid >> 6;
  const int wr = (wave & 1) * 32, wc = (wave >> 1) * 64;
  const int c = blockIdx.y;
  const int m0 = c * 64;
  const int n0 = blockIdx.x * 128;
  const int frow = lane & 15, fko = (lane >> 4) * 8;
  const unsigned short* Ab = sigbf + (size_t)(m0 + wr + frow) * H + fko;
  const unsigned short* Bb = Bcat + (size_t)(n0 + wc + frow) * K + fko;
  f32x4 acc[2][4];
#pragma unroll
  for (int i = 0; i < 2; i++)
#pragma unroll
    for (int j = 0; j < 4; j++) acc[i][j] = (f32x4){0.f, 0.f, 0.f, 0.f};

#pragma unroll
  for (int k0 = 0; k0 < K; k0 += 32) {
    short8 af[2], bf[4];
    af[0] = *(const short8*)(Ab + k0);
    af[1] = *(const short8*)(Ab + 16 * H + k0);
#pragma unroll
    for (int j = 0; j < 4; j++) bf[j] = *(const short8*)(Bb + j * 16 * K + k0);
#pragma unroll
    for (int i = 0; i < 2; i++)
#pragma unroll
      for (int j = 0; j < 4; j++)
        acc[i][j] = __builtin_amdgcn_mfma_f32_16x16x32_bf16(af[i], bf[j], acc[i][j], 0, 0, 0);
  }

  // ---- epilogue: dump acc (fp32) to LDS, then in-block chunk scan ----
  const int crow = (lane >> 4) * 4, ccol = wc + (lane & 15);
#pragma unroll
  for (int i = 0; i < 2; i++)
#pragma unroll
    for (int j = 0; j < 4; j++)
#pragma unroll
      for (int g = 0; g < 4; g++)
        sEpi[(wr + i * 16 + crow + g) * LDEP + ccol + j * 16] = acc[i][j][g];
  __syncthreads();

  if (tid < 64) {
    const int pl = tid;                 // local pair 0..63
    const int gp = (n0 >> 1) + pl;      // global p
    float lbr, lbi;
    lambda_bar_of(lam, lstep, gp, lbr, lbi);
    float xr = 0.f, xi = 0.f;
    const float* e = sEpi + 2 * pl;
    const size_t gbase = (size_t)m0 * N1 + n0 + 2 * pl;
    for (int tb = 0; tb < T; tb += 8) {
      float2 v[8];
#pragma unroll
      for (int u = 0; u < 8; u++) v[u] = *(const float2*)(e + (tb + u) * LDEP);
      unsigned ov[8];
#pragma unroll
      for (int u = 0; u < 8; u++) {
        float nr = fmaf(lbr, xr, fmaf(-lbi, xi, v[u].x));
        float ni = fmaf(lbr, xi, fmaf(lbi, xr, v[u].y));
        xr = nr; xi = ni;
        ov[u] = f2bf(xr) | (f2bf(xi) << 16);
      }
#pragma unroll
      for (int u = 0; u < 8; u++)
        *(unsigned*)(Xl + gbase + (size_t)(tb + u) * N1) = ov[u];
    }
    Sr[c * P + gp] = xr;
    Si[c * P + gp] = xi;
  }
}

// ---------------------------------------------------------------------------
// Parallel carry scan: 256 blocks (one per p) x 64 threads (1 wave).
// ---------------------------------------------------------------------------
__global__ __launch_bounds__(64) void k_carry2(const float* __restrict__ lam,
                                               const float* __restrict__ lstep,
                                               const float* __restrict__ Sr,
                                               const float* __restrict__ Si,
                                               float* __restrict__ car, float* __restrict__ cai) {
  const int p = blockIdx.x;
  const int t = threadIdx.x;  // 0..63
  float lr = lam[2 * p], li = lam[2 * p + 1];
  float st = expf(lstep[p]);
  float eT = expf((float)T * lr * st);
  float lTr = eT * cosf((float)T * li * st);
  float lTi = eT * sinf((float)T * li * st);
  float vr[8], vi[8];
#pragma unroll
  for (int u = 0; u < 8; u++) {
    vr[u] = Sr[(t * 8 + u) * P + p];
    vi[u] = Si[(t * 8 + u) * P + p];
  }
  float Br = 0.f, Bi = 0.f;
#pragma unroll
  for (int u = 0; u < 8; u++) {
    float nr = fmaf(lTr, Br, fmaf(-lTi, Bi, vr[u]));
    float ni = fmaf(lTr, Bi, fmaf(lTi, Br, vi[u]));
    Br = nr; Bi = ni;
  }
  float e8 = expf(8.0f * (float)T * lr * st);
  float Ar = e8 * cosf(8.0f * (float)T * li * st);
  float Ai = e8 * sinf(8.0f * (float)T * li * st);
#pragma unroll
  for (int d = 1; d < 64; d <<= 1) {
    float Aor = __shfl_up(Ar, d), Aoi = __shfl_up(Ai, d);
    float Bor = __shfl_up(Br, d), Boi = __shfl_up(Bi, d);
    if (t >= d) {
      float nBr = Ar * Bor - Ai * Boi + Br;
      float nBi = Ar * Boi + Ai * Bor + Bi;
      float nAr = Aor * Ar - Aoi * Ai;
      float nAi = Aor * Ai + Aoi * Ar;
      Br = nBr; Bi = nBi; Ar = nAr; Ai = nAi;
    }
  }
  float cr = __shfl_up(Br, 1), ci = __shfl_up(Bi, 1);
  if (t == 0) { cr = 0.f; ci = 0.f; }
#pragma unroll
  for (int u = 0; u < 8; u++) {
    car[(t * 8 + u) * P + p] = cr;
    cai[(t * 8 + u) * P + p] = ci;
    float nr = fmaf(lTr, cr, fmaf(-lTi, ci, vr[u]));
    float ni = fmaf(lTr, ci, fmaf(lTi, cr, vi[u]));
    cr = nr; ci = ni;
  }
}

// ---------------------------------------------------------------------------
// GEMM2: barrier-free, zero LDS. Tile 64x128 (1 chunk x 128 h), 4 waves of
// 32x64. A-frags built in registers: Xl(bf16) + pow[t]*carry[c] fixup (fp32).
// B (Ccat, L2-resident) direct to fragments. grid (H/128, NC) = (2, 512).
// ---------------------------------------------------------------------------
__global__ __launch_bounds__(256) void k_gemm2(const unsigned short* __restrict__ Xl,
                                               const unsigned short* __restrict__ Ccat,
                                               const float* __restrict__ powr,
                                               const float* __restrict__ powi,
                                               const float* __restrict__ car,
                                               const float* __restrict__ cai,
                                               const unsigned short* __restrict__ sigbf,
                                               const float* __restrict__ Dv,
                                               float* __restrict__ out) {
  constexpr int K = 512;
  const int tid = threadIdx.x;
  const int lane = tid & 63;
  const int wave = tid >> 6;
  const int wr = (wave & 1) * 32, wc = (wave >> 1) * 64;
  const int c = blockIdx.y;
  const int m0 = c * 64;
  const int n0 = blockIdx.x * 128;
  const int frow = lane & 15, fko = (lane >> 4) * 8;
  const int pq = (lane >> 4) * 4;             // pair offset within k-slice
  const unsigned short* Ab = Xl + (size_t)(m0 + wr + frow) * N1 + fko;
  const unsigned short* Bb = Ccat + (size_t)(n0 + wc + frow) * K + fko;
  const float* pw0r = powr + (wr + frow) * P;
  const float* pw0i = powi + (wr + frow) * P;
  const float* pw1r = powr + (wr + 16 + frow) * P;
  const float* pw1i = powi + (wr + 16 + frow) * P;
  const float* crb = car + c * P;
  const float* cib = cai + c * P;
  f32x4 acc[2][4];
#pragma unroll
  for (int i = 0; i < 2; i++)
#pragma unroll
    for (int j = 0; j < 4; j++) acc[i][j] = (f32x4){0.f, 0.f, 0.f, 0.f};

#pragma unroll 4
  for (int k0 = 0; k0 < K; k0 += 32) {
    const int p0 = (k0 >> 1) + pq;
    uint4 x0 = *(const uint4*)(Ab + k0);
    uint4 x1 = *(const uint4*)(Ab + 16 * N1 + k0);
    float4 a0r = *(const float4*)(pw0r + p0), a0i = *(const float4*)(pw0i + p0);
    float4 a1r = *(const float4*)(pw1r + p0), a1i = *(const float4*)(pw1i + p0);
    float4 g4r = *(const float4*)(crb + p0), g4i = *(const float4*)(cib + p0);
    float grv[4] = {g4r.x, g4r.y, g4r.z, g4r.w};
    float giv[4] = {g4i.x, g4i.y, g4i.z, g4i.w};
    s8u4 A0, A1;
    {
      unsigned xw[4] = {x0.x, x0.y, x0.z, x0.w};
      float pr[4] = {a0r.x, a0r.y, a0r.z, a0r.w};
      float pi_[4] = {a0i.x, a0i.y, a0i.z, a0i.w};
      unsigned wo[4];
#pragma unroll
      for (int j = 0; j < 4; j++) {
        float xgr = fmaf(pr[j], grv[j], fmaf(-pi_[j], giv[j], bf_lo(xw[j])));
        float xgi = fmaf(pr[j], giv[j], fmaf(pi_[j], grv[j], bf_hi(xw[j])));
        wo[j] = f2bf(xgr) | (f2bf(xgi) << 16);
      }
      A0.u.x = wo[0]; A0.u.y = wo[1]; A0.u.z = wo[2]; A0.u.w = wo[3];
    }
    {
      unsigned xw[4] = {x1.x, x1.y, x1.z, x1.w};
      float pr[4] = {a1r.x, a1r.y, a1r.z, a1r.w};
      float pi_[4] = {a1i.x, a1i.y, a1i.z, a1i.w};
      unsigned wo[4];
#pragma unroll
      for (int j = 0; j < 4; j++) {
        float xgr = fmaf(pr[j], grv[j], fmaf(-pi_[j], giv[j], bf_lo(xw[j])));
        float xgi = fmaf(pr[j], giv[j], fmaf(pi_[j], grv[j], bf_hi(xw[j])));
        wo[j] = f2bf(xgr) | (f2bf(xgi) << 16);
      }
      A1.u.x = wo[0]; A1.u.y = wo[1]; A1.u.z = wo[2]; A1.u.w = wo[3];
    }
    short8 bf[4];
#pragma unroll
    for (int j = 0; j < 4; j++) bf[j] = *(const short8*)(Bb + j * 16 * K + k0);
#pragma unroll
    for (int j = 0; j < 4; j++) {
      acc[0][j] = __builtin_amdgcn_mfma_f32_16x16x32_bf16(A0.s, bf[j], acc[0][j], 0, 0, 0);
      acc[1][j] = __builtin_amdgcn_mfma_f32_16x16x32_bf16(A1.s, bf[j], acc[1][j], 0, 0, 0);
    }
  }

  const int crow = (lane >> 4) * 4, ccol = wc + (lane & 15);
  float dcol[4];
#pragma unroll
  for (int j = 0; j < 4; j++) dcol[j] = Dv[n0 + ccol + j * 16];
#pragma unroll
  for (int i = 0; i < 2; i++)
#pragma unroll
    for (int j = 0; j < 4; j++) {
      int col = n0 + ccol + j * 16;
#pragma unroll
      for (int g = 0; g < 4; g++) {
        int row = m0 + wr + i * 16 + crow + g;
        float sv = __uint_as_float((unsigned)sigbf[(size_t)row * H + col] << 16);
        out[(size_t)row * H + col] = acc[i][j][g] + dcol[j] * sv;
      }
    }
}

// ---------------------------------------------------------------------------
// Launch
// ---------------------------------------------------------------------------
extern "C" void kernel_launch(void* const* d_in, const int* in_sizes, int n_in,
                              void* d_out, int out_size, void* d_ws, size_t ws_size,
                              hipStream_t stream) {
  const float* sig = (const float*)d_in[0];   // (L,H)
  const float* lam = (const float*)d_in[1];   // (P,2)
  const float* Bri = (const float*)d_in[2];   // (P,H,2)
  const float* Cri = (const float*)d_in[3];   // (H,P,2)
  const float* Dv  = (const float*)d_in[4];   // (H,)
  const float* lst = (const float*)d_in[5];   // (P,)
  float* out = (float*)d_out;

  // workspace layout (~52 MB)
  unsigned short* sigbf = (unsigned short*)d_ws;            // L*H bf16
  unsigned short* Bcat  = sigbf + (size_t)L * H;            // N1*H bf16
  unsigned short* Ccat  = Bcat + (size_t)N1 * H;            // H*N1 bf16
  unsigned short* Xl    = Ccat + (size_t)H * N1;            // L*N1 bf16 (x_local)
  float* powr = (float*)(Xl + (size_t)L * N1);              // T*P
  float* powi = powr + T * P;
  float* Sr   = powi + T * P;                               // NC*P
  float* Si   = Sr + NC * P;
  float* car  = Si + NC * P;
  float* cai  = car + NC * P;

  k_prep2<<<4096 + 1088, 256, 0, stream>>>(sig, lam, lst, Bri, Cri,
                                           sigbf, Bcat, Ccat, powr, powi);
  dim3 g1(N1 / 128, NC);
  k_gemm1<<<g1, 256, 0, stream>>>(sigbf, Bcat, lam, lst, Xl, Sr, Si);
  k_carry2<<<P, 64, 0, stream>>>(lam, lst, Sr, Si, car, cai);
  dim3 g2(H / 128, NC);
  k_gemm2<<<g2, 256, 0, stream>>>(Xl, Ccat, powr, powi, car, cai, sigbf, Dv, out);
}

// Round 7
// 175.060 us; speedup vs baseline: 1.2746x; 1.2746x over previous
//
#include <hip/hip_runtime.h>
#include <math.h>

constexpr int L = 32768;
constexpr int H = 256;
constexpr int P = 256;
constexpr int T = 64;        // scan chunk length == row tile
constexpr int NC = L / T;    // 512 chunks
constexpr int N1 = 2 * P;    // 512 cat width, col = 2p+{0:re,1:im}
constexpr int LDEP = 130;    // epilogue LDS row stride (floats)

typedef __attribute__((ext_vector_type(8))) short short8;
typedef __attribute__((ext_vector_type(4))) float f32x4;

// ---------------- bf16 helpers (RNE) ----------------
__device__ __forceinline__ unsigned f2bf(float f) {
  unsigned u = __float_as_uint(f);
  return (u + 0x7FFFu + ((u >> 16) & 1u)) >> 16;
}
__device__ __forceinline__ float bf_lo(unsigned u) { return __uint_as_float(u << 16); }
__device__ __forceinline__ float bf_hi(unsigned u) { return __uint_as_float(u & 0xFFFF0000u); }

__device__ __forceinline__ void lambda_bar_of(const float* __restrict__ lam,
                                              const float* __restrict__ lstep,
                                              int p, float& lbr, float& lbi) {
  float lr = lam[2 * p], li = lam[2 * p + 1];
  float st = expf(lstep[p]);
  float ea = expf(lr * st);
  lbr = ea * cosf(li * st);
  lbi = ea * sinf(li * st);
}

// fixup: one packed bf16 pair (re,im) += pow*carry (complex, fp32)
__device__ __forceinline__ unsigned fix2(unsigned w, float pr, float pi, float cr, float ci) {
  float xgr = fmaf(pr, cr, fmaf(-pi, ci, bf_lo(w)));
  float xgi = fmaf(pr, ci, fmaf(pi, cr, bf_hi(w)));
  return f2bf(xgr) | (f2bf(xgi) << 16);
}

// ===========================================================================
// Swizzled fragment layout (16x16x32 bf16 MFMA):
//   slab(r16, kb) = 64 lanes x 16 B; lane = (row&15) + 16*((k>>3)&3),
//   lane's 8 elements are k = kb*32 + (lane>>4)*8 + 0..7.
//   A_sw slabs indexed r16*(K/32)+kb; load = slab*1024B + lane*16B (coalesced).
// ===========================================================================

// ---------------------------------------------------------------------------
// k_prep: builds everything swizzled.
//  bx <  2048 : sig fp32 -> Asw (bf16, swizzled) via LDS transpose
//  bx <  2112 : Bsw  (N1 x 256, swizzled B_bar cat rows 2p/2p+1 = Re/Im)
//  bx <  2176 : Csw  (256 x N1, swizzled C cat cols 2p/2p+1 = Re/-Im)
//  bx <  2208 : powsw (fp32, pair-interleaved, A-frag swizzled, t16 x kb slabs)
// ---------------------------------------------------------------------------
__global__ __launch_bounds__(256) void k_prep(const float* __restrict__ sig,
                                              const float* __restrict__ lam,
                                              const float* __restrict__ lstep,
                                              const float* __restrict__ Bri,
                                              const float* __restrict__ Cri,
                                              unsigned short* __restrict__ Asw,
                                              unsigned short* __restrict__ Bsw,
                                              unsigned short* __restrict__ Csw,
                                              float* __restrict__ powsw) {
  __shared__ __align__(16) unsigned short plds[16 * 272];
  const int tid = threadIdx.x, bx = blockIdx.x;
  if (bx < 2048) {  // one 16-row band of sig
    const float4* sig4 = (const float4*)sig;
    size_t fb = (size_t)bx * 1024;
#pragma unroll
    for (int u = 0; u < 4; u++) {
      int idx = u * 256 + tid;
      float4 a = sig4[fb + idx];
      int row = idx >> 6, colf = (idx & 63) * 4;
      uint2 w;
      w.x = f2bf(a.x) | (f2bf(a.y) << 16);
      w.y = f2bf(a.z) | (f2bf(a.w) << 16);
      *(uint2*)(plds + row * 272 + colf) = w;
    }
    __syncthreads();
    uint4* dst = (uint4*)Asw + (size_t)bx * 512;
#pragma unroll
    for (int u = 0; u < 2; u++) {
      int s = u * 256 + tid;
      int kb = s >> 6, ln = s & 63;
      int row = ln & 15, k0 = kb * 32 + (ln >> 4) * 8;
      dst[s] = *(const uint4*)(plds + row * 272 + k0);
    }
    return;
  }
  if (bx < 2112) {  // Bsw
    int o = (bx - 2048) * 256 + tid;  // < 16384 uint4 slots
    int slab = o >> 6, ln = o & 63;
    int n16 = slab >> 3, kb = slab & 7;
    int n = n16 * 16 + (ln & 15);
    int k0 = kb * 32 + (ln >> 4) * 8;
    int p = n >> 1, comp = n & 1;
    float lr = lam[2 * p], li = lam[2 * p + 1];
    float st = expf(lstep[p]);
    float ea = expf(lr * st);
    float lbr = ea * cosf(li * st), lbi = ea * sinf(li * st);
    float inv = 1.0f / (lr * lr + li * li);
    float nr = lbr - 1.0f;
    float fr = (nr * lr + lbi * li) * inv, fi = (lbi * lr - nr * li) * inv;
    unsigned wv[4];
#pragma unroll
    for (int m = 0; m < 4; m++) {
      unsigned lh[2];
#pragma unroll
      for (int h2 = 0; h2 < 2; h2++) {
        int k = k0 + m * 2 + h2;
        float br = Bri[2 * (p * H + k)], bi = Bri[2 * (p * H + k) + 1];
        float v = comp ? (fr * bi + fi * br) : (fr * br - fi * bi);
        lh[h2] = f2bf(v);
      }
      wv[m] = lh[0] | (lh[1] << 16);
    }
    uint4 w; w.x = wv[0]; w.y = wv[1]; w.z = wv[2]; w.w = wv[3];
    ((uint4*)Bsw)[o] = w;
    return;
  }
  if (bx < 2176) {  // Csw
    int o = (bx - 2112) * 256 + tid;  // < 16384
    int slab = o >> 6, ln = o & 63;
    int h16 = slab >> 4, kb = slab & 15;
    int h = h16 * 16 + (ln & 15);
    int k0 = kb * 32 + (ln >> 4) * 8;
    unsigned wv[4];
#pragma unroll
    for (int m = 0; m < 4; m++) {
      unsigned lh[2];
#pragma unroll
      for (int h2 = 0; h2 < 2; h2++) {
        int kcat = k0 + m * 2 + h2;
        int p = kcat >> 1;
        float v = (kcat & 1) ? -Cri[2 * (h * P + p) + 1] : Cri[2 * (h * P + p)];
        lh[h2] = f2bf(v);
      }
      wv[m] = lh[0] | (lh[1] << 16);
    }
    uint4 w; w.x = wv[0]; w.y = wv[1]; w.z = wv[2]; w.w = wv[3];
    ((uint4*)Csw)[o] = w;
    return;
  }
  {  // powsw: lambda^(t+1), fp32, pair-interleaved, swizzled
    int o = (bx - 2176) * 256 + tid;  // < 8192 float4 slots
    int s = o >> 1, half = o & 1;
    int ln = s & 63, slab = s >> 6;
    int t16 = slab >> 4, kb = slab & 15;
    int t = t16 * 16 + (ln & 15);
    int kbase = kb * 32 + (ln >> 4) * 8 + half * 4;
    float e = (float)(t + 1);
    float4 v;
    {
      int p = kbase >> 1;
      float lr = lam[2 * p], li = lam[2 * p + 1], st = expf(lstep[p]);
      float er = expf(e * lr * st);
      v.x = er * cosf(e * li * st);
      v.y = er * sinf(e * li * st);
    }
    {
      int p = (kbase >> 1) + 1;
      float lr = lam[2 * p], li = lam[2 * p + 1], st = expf(lstep[p]);
      float er = expf(e * lr * st);
      v.z = er * cosf(e * li * st);
      v.w = er * sinf(e * li * st);
    }
    ((float4*)powsw)[o] = v;
  }
}

// ---------------------------------------------------------------------------
// GEMM1: Bu tile = Asw(sig) @ Bsw^T. Barrier-free K-loop, fully coalesced
// fragment loads (swizzled layouts). Tile 64x128 (1 chunk), 4 waves 32x64.
// Epilogue: dump acc -> LDS, in-block chunk scan, write x_local straight into
// gemm2's swizzled A layout (Xsw) + chunk-final S. grid (4, 512).
// ---------------------------------------------------------------------------
__global__ __launch_bounds__(256) void k_gemm1(const unsigned short* __restrict__ Asw,
                                               const unsigned short* __restrict__ Bsw,
                                               const float* __restrict__ lam,
                                               const float* __restrict__ lstep,
                                               unsigned short* __restrict__ Xsw,
                                               float* __restrict__ Sr,
                                               float* __restrict__ Si) {
  __shared__ __align__(16) float sEpi[T * LDEP];  // 33.3 KB
  const int tid = threadIdx.x, lane = tid & 63, wave = tid >> 6;
  const int wr = (wave & 1) * 32, wc = (wave >> 1) * 64;
  const int c = blockIdx.y, n0 = blockIdx.x * 128;
  const unsigned short* Ab = Asw + ((size_t)(c * 4 + (wr >> 4)) * 8) * 512 + lane * 8;
  const unsigned short* Bb = Bsw + ((size_t)((n0 + wc) >> 4) * 8) * 512 + lane * 8;
  f32x4 acc[2][4];
#pragma unroll
  for (int i = 0; i < 2; i++)
#pragma unroll
    for (int j = 0; j < 4; j++) acc[i][j] = (f32x4){0.f, 0.f, 0.f, 0.f};

#pragma unroll 4
  for (int kb = 0; kb < 8; kb++) {
    short8 af[2], bf[4];
    af[0] = *(const short8*)(Ab + kb * 512);
    af[1] = *(const short8*)(Ab + 8 * 512 + kb * 512);
#pragma unroll
    for (int j = 0; j < 4; j++) bf[j] = *(const short8*)(Bb + j * 8 * 512 + kb * 512);
#pragma unroll
    for (int i = 0; i < 2; i++)
#pragma unroll
      for (int j = 0; j < 4; j++)
        acc[i][j] = __builtin_amdgcn_mfma_f32_16x16x32_bf16(af[i], bf[j], acc[i][j], 0, 0, 0);
  }

  // epilogue: dump (C-layout) then chunk-local scan
  const int crow = (lane >> 4) * 4, ccol = lane & 15;
#pragma unroll
  for (int i = 0; i < 2; i++)
#pragma unroll
    for (int j = 0; j < 4; j++)
#pragma unroll
      for (int g = 0; g < 4; g++)
        sEpi[(wr + i * 16 + crow + g) * LDEP + (wc + j * 16 + ccol)] = acc[i][j][g];
  __syncthreads();

  if (tid < 64) {
    const int pl = tid;
    const int gp = (n0 >> 1) + pl;
    float lbr, lbi;
    lambda_bar_of(lam, lstep, gp, lbr, lbi);
    const int kbx = (n0 >> 5) + (pl >> 4);
    const int slot16 = 16 * ((pl >> 2) & 3);
    const int off2 = (pl & 3) * 2;
    float xr = 0.f, xi = 0.f;
    const float* e = sEpi + 2 * pl;
    for (int tb = 0; tb < T; tb += 8) {
      float2 v[8];
#pragma unroll
      for (int u = 0; u < 8; u++) v[u] = *(const float2*)(e + (tb + u) * LDEP);
      unsigned ov[8];
#pragma unroll
      for (int u = 0; u < 8; u++) {
        float nr = fmaf(lbr, xr, fmaf(-lbi, xi, v[u].x));
        float ni = fmaf(lbr, xi, fmaf(lbi, xr, v[u].y));
        xr = nr; xi = ni;
        ov[u] = f2bf(xr) | (f2bf(xi) << 16);
      }
      size_t slabbase = ((size_t)(c * 4 + (tb >> 4)) * 16 + kbx) * 512;
#pragma unroll
      for (int u = 0; u < 8; u++)
        *(unsigned*)(Xsw + slabbase + ((tb & 15) + u + slot16) * 8 + off2) = ov[u];
    }
    Sr[c * P + gp] = xr;
    Si[c * P + gp] = xi;
  }
}

// ---------------------------------------------------------------------------
// Carry scan over chunks (1 block, 256 threads = p), coalesced, batch-32.
// Output carcat interleaved: carcat[c*512 + 2p] = (re, im).
// ---------------------------------------------------------------------------
__global__ __launch_bounds__(256) void k_carry(const float* __restrict__ lam,
                                               const float* __restrict__ lstep,
                                               const float* __restrict__ Sr,
                                               const float* __restrict__ Si,
                                               float* __restrict__ carcat) {
  const int p = threadIdx.x;
  float lr = lam[2 * p], li = lam[2 * p + 1];
  float st = expf(lstep[p]);
  float ea = expf((float)T * lr * st);
  float lTr = ea * cosf((float)T * li * st);
  float lTi = ea * sinf((float)T * li * st);
  float cr = 0.f, ci = 0.f;
  for (int c0 = 0; c0 < NC; c0 += 32) {
    float vr[32], vi[32];
#pragma unroll
    for (int u = 0; u < 32; u++) {
      vr[u] = Sr[(c0 + u) * P + p];
      vi[u] = Si[(c0 + u) * P + p];
    }
#pragma unroll
    for (int u = 0; u < 32; u++) {
      *(float2*)(carcat + (size_t)(c0 + u) * N1 + 2 * p) = make_float2(cr, ci);
      float nr = fmaf(lTr, cr, fmaf(-lTi, ci, vr[u]));
      float ni = fmaf(lTr, ci, fmaf(lTi, cr, vi[u]));
      cr = nr; ci = ni;
    }
  }
}

// ---------------------------------------------------------------------------
// GEMM2: y = (Xsw + pow*carry) @ Csw^T + D*u. Barrier-free, zero LDS, all
// loads coalesced (swizzled) or broadcast (carry). Tile 64x128, grid (2, 512).
// ---------------------------------------------------------------------------
__global__ __launch_bounds__(256) void k_gemm2(const unsigned short* __restrict__ Xsw,
                                               const unsigned short* __restrict__ Csw,
                                               const float* __restrict__ powsw,
                                               const float* __restrict__ carcat,
                                               const float* __restrict__ sig,
                                               const float* __restrict__ Dv,
                                               float* __restrict__ out) {
  const int tid = threadIdx.x, lane = tid & 63, wave = tid >> 6;
  const int wr = (wave & 1) * 32, wc = (wave >> 1) * 64;
  const int c = blockIdx.y, n0 = blockIdx.x * 128;
  const int m0 = c * 64;
  const unsigned short* Ab = Xsw + ((size_t)(c * 4 + (wr >> 4)) * 16) * 512 + lane * 8;
  const unsigned short* Bb = Csw + ((size_t)((n0 + wc) >> 4) * 16) * 512 + lane * 8;
  const float* Pw = powsw + ((size_t)(wr >> 4) * 16) * 512 + lane * 8;
  const float* Cw = carcat + (size_t)c * N1 + (lane >> 4) * 8;
  f32x4 acc[2][4];
#pragma unroll
  for (int i = 0; i < 2; i++)
#pragma unroll
    for (int j = 0; j < 4; j++) acc[i][j] = (f32x4){0.f, 0.f, 0.f, 0.f};

#pragma unroll 2
  for (int kb = 0; kb < 16; kb++) {
    uint4 x0 = *(const uint4*)(Ab + kb * 512);
    uint4 x1 = *(const uint4*)(Ab + 16 * 512 + kb * 512);
    float4 pa0 = *(const float4*)(Pw + kb * 512);
    float4 pb0 = *(const float4*)(Pw + kb * 512 + 4);
    float4 pa1 = *(const float4*)(Pw + 16 * 512 + kb * 512);
    float4 pb1 = *(const float4*)(Pw + 16 * 512 + kb * 512 + 4);
    float4 ca = *(const float4*)(Cw + kb * 32);
    float4 cb = *(const float4*)(Cw + kb * 32 + 4);
    short8 bf[4];
#pragma unroll
    for (int j = 0; j < 4; j++) bf[j] = *(const short8*)(Bb + j * 16 * 512 + kb * 512);
    union { short8 s; uint4 u; } A0, A1;
    A0.u.x = fix2(x0.x, pa0.x, pa0.y, ca.x, ca.y);
    A0.u.y = fix2(x0.y, pa0.z, pa0.w, ca.z, ca.w);
    A0.u.z = fix2(x0.z, pb0.x, pb0.y, cb.x, cb.y);
    A0.u.w = fix2(x0.w, pb0.z, pb0.w, cb.z, cb.w);
    A1.u.x = fix2(x1.x, pa1.x, pa1.y, ca.x, ca.y);
    A1.u.y = fix2(x1.y, pa1.z, pa1.w, ca.z, ca.w);
    A1.u.z = fix2(x1.z, pb1.x, pb1.y, cb.x, cb.y);
    A1.u.w = fix2(x1.w, pb1.z, pb1.w, cb.z, cb.w);
#pragma unroll
    for (int j = 0; j < 4; j++) {
      acc[0][j] = __builtin_amdgcn_mfma_f32_16x16x32_bf16(A0.s, bf[j], acc[0][j], 0, 0, 0);
      acc[1][j] = __builtin_amdgcn_mfma_f32_16x16x32_bf16(A1.s, bf[j], acc[1][j], 0, 0, 0);
    }
  }

  const int crow = (lane >> 4) * 4, ccol = lane & 15;
  float dcol[4];
#pragma unroll
  for (int j = 0; j < 4; j++) dcol[j] = Dv[n0 + wc + ccol + j * 16];
#pragma unroll
  for (int i = 0; i < 2; i++)
#pragma unroll
    for (int j = 0; j < 4; j++) {
      int col = n0 + wc + ccol + j * 16;
#pragma unroll
      for (int g = 0; g < 4; g++) {
        int row = m0 + wr + i * 16 + crow + g;
        out[(size_t)row * H + col] = acc[i][j][g] + dcol[j] * sig[(size_t)row * H + col];
      }
    }
}

// ---------------------------------------------------------------------------
// Launch
// ---------------------------------------------------------------------------
extern "C" void kernel_launch(void* const* d_in, const int* in_sizes, int n_in,
                              void* d_out, int out_size, void* d_ws, size_t ws_size,
                              hipStream_t stream) {
  const float* sig = (const float*)d_in[0];   // (L,H)
  const float* lam = (const float*)d_in[1];   // (P,2)
  const float* Bri = (const float*)d_in[2];   // (P,H,2)
  const float* Cri = (const float*)d_in[3];   // (H,P,2)
  const float* Dv  = (const float*)d_in[4];   // (H,)
  const float* lst = (const float*)d_in[5];   // (P,)
  float* out = (float*)d_out;

  // workspace (~52.6 MB)
  unsigned short* Asw = (unsigned short*)d_ws;        // L*H shorts (16 MB)
  unsigned short* Xsw = Asw + (size_t)L * H;          // L*N1 shorts (32 MB)
  unsigned short* Bsw = Xsw + (size_t)L * N1;         // N1*H shorts
  unsigned short* Csw = Bsw + (size_t)N1 * H;         // H*N1 shorts
  float* powsw  = (float*)(Csw + (size_t)H * N1);     // 64*512 floats
  float* Sr     = powsw + 64 * 512;                   // NC*P
  float* Si     = Sr + NC * P;
  float* carcat = Si + NC * P;                        // NC*N1 floats (1 MB)

  k_prep<<<2208, 256, 0, stream>>>(sig, lam, lst, Bri, Cri, Asw, Bsw, Csw, powsw);
  dim3 g1(N1 / 128, NC);
  k_gemm1<<<g1, 256, 0, stream>>>(Asw, Bsw, lam, lst, Xsw, Sr, Si);
  k_carry<<<1, 256, 0, stream>>>(lam, lst, Sr, Si, carcat);
  dim3 g2(H / 128, NC);
  k_gemm2<<<g2, 256, 0, stream>>>(Xsw, Csw, powsw, carcat, sig, Dv, out);
}